// Round 14
// baseline (142.702 us; speedup 1.0000x reference)
//
#include <hip/hip_runtime.h>
#include <stdint.h>

#define B_ 32
#define P_ 8732
#define C_ 21
#define TOPK 200
#define TGT 228        // count-search acceptance window center [200,256]
#define TGT0 300       // scatter pre-filter target count (mean; sigma~17)
#define SUBCAP 28      // per-(task,chunk) capacity; Poisson(8.8) P(>28)~1e-7
#define NCH2 35        // ceil(P_/256) chunks
#define NSLOT (NCH2 * SUBCAP)   // 980 slots/task
#define CONF_T 0.01f
#define NMS_T 0.45f
#define NTASK (B_ * C_)
#define GT 4           // tasks per detect block
#define HT 256         // threads per task
#define NTB (GT * HT)  // 1024
#define NBLK (NTASK / GT)   // 168 -> exactly 1 dispatch round on 256 CUs
#define KV4H 9         // slow-path strided load: ceil((P_/4)/HT)

__device__ __forceinline__ uint32_t f2s(float f) {
    uint32_t u = __float_as_uint(f);
    return (u & 0x80000000u) ? ~u : (u | 0x80000000u);
}
__device__ __forceinline__ float s2f(uint32_t s) {
    uint32_t b = (s & 0x80000000u) ? (s & 0x7FFFFFFFu) : ~s;
    return __uint_as_float(b);
}
__device__ __forceinline__ uint32_t keyof(float v) {
    return f2s((v > CONF_T) ? v : -1.0f);
}
__device__ __forceinline__ uint32_t thr0() {
    return f2s(1.0f - (float)TGT0 / (float)P_);   // folds to a constant
}

// conf (B,P,C) -> chunked per-task candidate lists. No atomics: ballot prefix
// assigns slots; lane-per-prior LDS reads (stride 21 coprime 32: conflict-free).
__global__ __launch_bounds__(256) void scatter_cands(const float* __restrict__ conf,
                                                     uint32_t* __restrict__ gccnt,
                                                     uint64_t* __restrict__ gcand) {
    const int b = blockIdx.x / NCH2;
    const int ch = blockIdx.x % NCH2;
    const int p0 = ch * 256;
    const int n = min(256, P_ - p0);          // 256 or 28
    const int tid = threadIdx.x;
    const int lane = tid & 63;
    const int wv = tid >> 6;                  // wave id: class slice 0..3
    __shared__ float tile[256 * C_];
    const float4* src4 = (const float4*)(conf + ((size_t)b * P_ + p0) * C_);
    float4* tile4 = (float4*)tile;
    const int tot4 = (n * C_) >> 2;
    for (int i = tid; i < tot4; i += 256) tile4[i] = src4[i];
    __syncthreads();
    const uint32_t T0 = thr0();
    const unsigned long long lmask = (1ull << lane) - 1ull;
    for (int c = (wv == 0 ? 4 : wv); c < C_; c += 4) {   // class 0 output zeroed: skip
        int base = 0;
        uint64_t* dst = gcand + ((size_t)(b * C_ + c) * NCH2 + ch) * SUBCAP;
        #pragma unroll
        for (int itp = 0; itp < 4; ++itp) {
            const int p = itp * 64 + lane;
            bool q = false; uint32_t key = 0;
            if (p < n) {
                key = keyof(tile[p * C_ + c]);   // conflict-free: stride 21 banks
                q = (key >= T0);
            }
            const unsigned long long bm = __ballot(q);
            if (q) {
                int pos = base + (int)__popcll(bm & lmask);
                if (pos < SUBCAP)
                    dst[pos] = ((uint64_t)key << 32) | (uint32_t)(~(uint32_t)(p0 + p));
            }
            base += (int)__popcll(bm);
        }
        if (lane == 0) gccnt[(size_t)(b * C_ + c) * NCH2 + ch] = (uint32_t)base;
    }
}

template<bool HASWS>
__global__ __launch_bounds__(NTB, 4) void detect_kernel(
    const float* __restrict__ loc, const float* __restrict__ prior,
    const uint32_t* __restrict__ gccnt, const uint64_t* __restrict__ gcand,
    const float* __restrict__ conf, float* __restrict__ out)
{
    const int tid = threadIdx.x;
    const int h   = tid >> 8;          // task quarter 0..3
    const int ht  = tid & 255;         // thread within task
    const int lane = tid & 63;
    const int task = blockIdx.x * GT + h;
    const int b = task / C_;
    const int c = task % C_;
    const bool live = (c != 0);        // c==0: output zeros, ride the barriers
    float* outp = out + (size_t)task * TOPK * 5;

    __shared__ uint64_t cand[GT][256];
    __shared__ float4 bbox[GT][TOPK];
    __shared__ float bs[GT][TOPK];
    __shared__ unsigned long long msk[GT][TOPK * 4];
    __shared__ unsigned long long vmask[GT][4];
    __shared__ int order[GT][TOPK];
    __shared__ int s_cnt[GT], s_nk[GT];
    __shared__ int s_c2[GT][2];
    __shared__ uint32_t s_ccnt[GT][NCH2];
    __shared__ int s_gc[GT], s_bad[GT], s_act[GT];

    const uint32_t T0 = thr0();

    // ---- zeroing + chunk-count load ----
    if (ht == 0) s_cnt[h] = 0;
    if (ht < 2) s_c2[h][ht] = 0;
    if (HASWS && ht < NCH2) s_ccnt[h][ht] = gccnt[(size_t)task * NCH2 + ht];
    for (int i = ht; i < TOPK * 4; i += HT) msk[h][i] = 0ull;
    __syncthreads();
    if (HASWS && ht < 64) {            // quarter's wave 0: total + overflow check
        uint32_t cc = (lane < NCH2) ? s_ccnt[h][lane] : 0u;
        int bad = (cc > SUBCAP) ? 1 : 0;
        int tot = (int)cc;
        #pragma unroll
        for (int d = 1; d < 64; d <<= 1) {
            tot += __shfl_down(tot, d);
            bad |= __shfl_down(bad, d);
        }
        if (lane == 0) { s_gc[h] = tot; s_bad[h] = bad; }
    }
    __syncthreads();

    const bool fast = HASWS && live && !s_bad[h] && s_gc[h] >= TOPK;   // ~always
    const int gc = fast ? s_gc[h] : 0;

    // ---- load candidate keys (fast: <=4 slots/thread; slow: strided conf) ----
    uint64_t vc[4] = {0, 0, 0, 0};
    bool val[4] = {false, false, false, false};
    uint4 kv[KV4H];
    #pragma unroll
    for (int r = 0; r < KV4H; ++r) kv[r] = make_uint4(0u, 0u, 0u, 0u);
    if (fast) {
        const uint64_t* gp = gcand + (size_t)task * NSLOT;
        #pragma unroll
        for (int k = 0; k < 4; ++k) {
            const int s = ht + k * HT;
            if (s < NSLOT) {
                const int chh = s / SUBCAP, ii = s - chh * SUBCAP;
                if (ii < (int)s_ccnt[h][chh]) { vc[k] = gp[s]; val[k] = true; }
            }
        }
    } else if (live) {
        const float* sp = conf + (size_t)b * P_ * C_ + c;
        #pragma unroll
        for (int r = 0; r < KV4H; ++r) {
            uint32_t uu[4];
            #pragma unroll
            for (int q = 0; q < 4; ++q) {
                const int p = (ht + r * HT) * 4 + q;
                uu[q] = (p < P_) ? keyof(sp[(size_t)p * C_]) : 0u;
            }
            kv[r] = make_uint4(uu[0], uu[1], uu[2], uu[3]);
        }
    }

    // ---- unified interpolated count-search (per quarter; coupled barriers) ----
    bool active = false;
    uint32_t t = 0, lo = 0, hi = 0xFFFFFFFFu, vthr = 0;
    int it2 = 0;
    if (!live) {
        vthr = 0xFFFFFFFFu;
    } else if (fast) {
        lo = T0; vthr = T0;
        if (gc > 256) {
            const float sc = s2f(T0);
            const float sn = 1.0f - (1.0f - sc) * (float)TGT / (float)gc;
            t = f2s(sn);
            if (!(t > lo && t < hi)) t = lo + ((hi - lo) >> 1);
            active = true;
        }
    } else {
        t = f2s(1.0f - (float)TGT / (float)P_);
        active = true;
    }
    if (ht == 0) s_act[h] = active ? 1 : 0;
    __syncthreads();

    for (int bit = 0; ; ++bit) {
        if (!(s_act[0] | s_act[1] | s_act[2] | s_act[3])) break;
        const int slot = bit & 1;
        int my = 0;
        if (active) {
            if (fast) {
                #pragma unroll
                for (int k = 0; k < 4; ++k)
                    my += (val[k] && (uint32_t)(vc[k] >> 32) >= t) ? 1 : 0;
            } else {
                #pragma unroll
                for (int r = 0; r < KV4H; ++r)
                    my += (kv[r].x >= t) + (kv[r].y >= t) + (kv[r].z >= t) + (kv[r].w >= t);
            }
        }
        #pragma unroll
        for (int d = 1; d < 64; d <<= 1) my += __shfl_down(my, d);
        if (lane == 0 && my) atomicAdd(&s_c2[h][slot], my);
        __syncthreads();
        const int cnt = s_c2[h][slot];
        __syncthreads();
        if (ht == 0) s_c2[h][slot] = 0;
        if (active) {
            if (cnt >= TOPK && cnt <= 256) { vthr = t; active = false; }
            else {
                if (cnt > 256) lo = t; else hi = t;
                if (hi - lo <= 1) { vthr = lo; active = false; }
                else {
                    uint32_t tn = 0;
                    bool bis = (it2 >= 8) || (cnt == 0);
                    if (!bis) {
                        const float sc = s2f(t);
                        const float sn = 1.0f - (1.0f - sc) * (float)TGT / (float)cnt;
                        tn = f2s(sn);
                        if (!(tn > lo && tn < hi)) bis = true;
                    }
                    if (bis) tn = lo + ((hi - lo) >> 1);
                    t = tn;
                }
                ++it2;
            }
        }
        if (ht == 0) s_act[h] = active ? 1 : 0;
        __syncthreads();
    }

    // ---- compact candidates >= vthr ----
    if (live) {
        if (fast) {
            #pragma unroll
            for (int k = 0; k < 4; ++k)
                if (val[k] && (uint32_t)(vc[k] >> 32) >= vthr) {
                    int pos = atomicAdd(&s_cnt[h], 1);
                    if (pos < 256) cand[h][pos] = vc[k];
                }
        } else {
            #pragma unroll
            for (int r = 0; r < KV4H; ++r) {
                const int pb = (ht + r * HT) * 4;
                uint32_t uu[4] = {kv[r].x, kv[r].y, kv[r].z, kv[r].w};
                #pragma unroll
                for (int q = 0; q < 4; ++q)
                    if (uu[q] >= vthr) {
                        int pos = atomicAdd(&s_cnt[h], 1);
                        if (pos < 256)
                            cand[h][pos] = ((uint64_t)uu[q] << 32) | (uint32_t)(~(uint32_t)(pb + q));
                    }
            }
        }
    }
    __syncthreads();
    if (ht >= s_cnt[h]) cand[h][ht] = 0ull;   // pad sorts to the end
    __syncthreads();

    // ---- bitonic sort 256 keys desc (val desc, idx asc) == jax.lax.top_k ----
    uint64_t v = cand[h][ht];
    for (int kk = 2; kk <= 256; kk <<= 1) {
        for (int j = kk >> 1; j > 0; j >>= 1) {
            if (j >= 64) {
                __syncthreads();
                cand[h][ht] = v;
                __syncthreads();
                uint64_t pv = cand[h][ht ^ j];
                bool keepmax = (((ht & j) == 0) == ((ht & kk) == 0));
                v = keepmax ? (v > pv ? v : pv) : (v < pv ? v : pv);
            } else {
                uint64_t pv = __shfl_xor(v, j);
                bool keepmax = (((ht & j) == 0) == ((ht & kk) == 0));
                v = keepmax ? (v > pv ? v : pv) : (v < pv ? v : pv);
            }
        }
    }

    // ---- decode top-200 boxes (exact ref f32 op order, no contraction) ----
    float my_sc = -1.0f;
    if (live && ht < TOPK) {
        uint32_t su = (uint32_t)(v >> 32);
        int p = (int)(~(uint32_t)v);
        my_sc = s2f(su);
        const float4 l4 = *(const float4*)(loc + ((size_t)b * P_ + p) * 4);
        const float4 pr = *(const float4*)(prior + (size_t)p * 4);
        float cx = __fadd_rn(pr.x, __fmul_rn(__fmul_rn(l4.x, 0.1f), pr.z));
        float cy = __fadd_rn(pr.y, __fmul_rn(__fmul_rn(l4.y, 0.1f), pr.w));
        float ew = (float)exp((double)__fmul_rn(l4.z, 0.2f));
        float eh = (float)exp((double)__fmul_rn(l4.w, 0.2f));
        float w  = __fmul_rn(pr.z, ew);
        float hh = __fmul_rn(pr.w, eh);
        float x1 = __fsub_rn(cx, __fmul_rn(w, 0.5f));
        float y1 = __fsub_rn(cy, __fmul_rn(hh, 0.5f));
        float x2 = __fadd_rn(x1, w);
        float y2 = __fadd_rn(y1, hh);
        bs[h][ht] = my_sc;
        bbox[h][ht] = make_float4(x1, y1, x2, y2);
    }
    {
        unsigned long long bm = __ballot(live && ht < TOPK && my_sc > CONF_T);
        if (lane == 0) vmask[h][ht >> 6] = bm;
    }
    __syncthreads();

    // ---- pairwise IoU: balanced row-pairing (2 sub-lanes), areas inline ----
    if (live && ht < 200) {
        const int rp = ht >> 1;
        const int s  = ht & 1;
        #pragma unroll
        for (int pass = 0; pass < 2; ++pass) {
            const int j  = pass ? (199 - rp) : rp;
            const int i0 = j + 1 + s;
            const float4 bj = bbox[h][j];
            const float  aj = __fmul_rn(__fsub_rn(bj.z, bj.x), __fsub_rn(bj.w, bj.y));
            for (int i = i0; i < TOPK; i += 2) {
                const float4 bi = bbox[h][i];
                float xx1 = fmaxf(bj.x, bi.x);
                float yy1 = fmaxf(bj.y, bi.y);
                float xx2 = fminf(bj.z, bi.z);
                float yy2 = fminf(bj.w, bi.w);
                float dx = fmaxf(__fsub_rn(xx2, xx1), 0.0f);
                float dy = fmaxf(__fsub_rn(yy2, yy1), 0.0f);
                float inter = __fmul_rn(dx, dy);
                if (inter > 0.0f) {
                    float ai = __fmul_rn(__fsub_rn(bi.z, bi.x), __fsub_rn(bi.w, bi.y));
                    float uni = __fsub_rn(__fadd_rn(aj, ai), inter);
                    float t45 = __fmul_rn(NMS_T, uni);
                    float mar = __fmul_rn(t45, 1e-6f);
                    bool sup;
                    if (inter > __fadd_rn(t45, mar)) sup = true;
                    else if (inter < __fsub_rn(t45, mar)) sup = false;
                    else sup = (inter / uni > NMS_T);   // exact IEEE path, tie band only
                    if (sup) atomicOr(&msk[h][j * 4 + (i >> 6)], 1ull << (i & 63));
                }
            }
        }
    }
    __syncthreads();

    // ---- greedy NMS: word-blocked per-quarter wave-0 scan ----
    if (ht < 64) {
        const int L = ht;
        auto or_reduce = [&](unsigned long long x) {
            #pragma unroll
            for (int d = 1; d < 64; d <<= 1) x |= __shfl_xor(x, d);
            return x;
        };
        unsigned long long s1 = 0, s2 = 0, s3 = 0;
        int nk = 0;
        #pragma unroll
        for (int w = 0; w < 4; ++w) {
            const int j = (w << 6) | L;
            unsigned long long r0 = 0, r1 = 0, r2 = 0, r3 = 0;
            if (j < TOPK) {
                const unsigned long long* mr = &msk[h][j * 4];
                r0 = mr[0]; r1 = mr[1]; r2 = mr[2]; r3 = mr[3];
            }
            const unsigned long long rself = (w == 0) ? r0 : (w == 1) ? r1
                                           : (w == 2) ? r2 : r3;
            unsigned long long sw = (w == 0) ? 0ull : (w == 1) ? s1
                                  : (w == 2) ? s2 : s3;
            unsigned long long alive = vmask[h][w] & ~sw;
            unsigned long long pm = 0;
            while (alive) {
                int jl = __ffsll(alive) - 1;
                if (L == 0) order[h][nk] = (w << 6) | jl;
                ++nk;
                sw |= __shfl(rself, jl);
                pm |= (1ull << jl);
                alive &= ~(sw | (1ull << jl));
            }
            if (pm) {   // deferred cross-word OR (mask bits are i>j only)
                const bool picked = (pm >> L) & 1ull;
                if (w == 0) {
                    s1 |= or_reduce(picked ? r1 : 0ull);
                    s2 |= or_reduce(picked ? r2 : 0ull);
                    s3 |= or_reduce(picked ? r3 : 0ull);
                } else if (w == 1) {
                    s2 |= or_reduce(picked ? r2 : 0ull);
                    s3 |= or_reduce(picked ? r3 : 0ull);
                } else if (w == 2) {
                    s3 |= or_reduce(picked ? r3 : 0ull);
                }
            }
        }
        if (L == 0) s_nk[h] = nk;
    }
    __syncthreads();

    // ---- compacted output (c==0 quarter: nk=0 -> zeros) ----
    const int nk = live ? s_nk[h] : 0;
    for (int e = ht; e < TOPK * 5; e += HT) {
        int r = e / 5;
        int f = e - r * 5;
        float val2 = 0.0f;
        if (r < nk) {
            int j = order[h][r];
            float4 bb = bbox[h][j];
            val2 = (f == 0) ? bs[h][j] : (f == 1) ? bb.x : (f == 2) ? bb.y
                 : (f == 3) ? bb.z : bb.w;
        }
        outp[e] = val2;
    }
}

extern "C" void kernel_launch(void* const* d_in, const int* in_sizes, int n_in,
                              void* d_out, int out_size, void* d_ws, size_t ws_size,
                              hipStream_t stream) {
    const float* loc   = (const float*)d_in[0];
    const float* conf  = (const float*)d_in[1];
    const float* prior = (const float*)d_in[2];
    float* out = (float*)d_out;

    const size_t cnt_bytes  = (size_t)NTASK * NCH2 * sizeof(uint32_t);   // 8-aligned
    const size_t cand_bytes = (size_t)NTASK * NSLOT * sizeof(uint64_t);  // ~5.3 MB
    if (ws_size >= cnt_bytes + cand_bytes) {
        uint32_t* gccnt = (uint32_t*)d_ws;
        uint64_t* gcand = (uint64_t*)((char*)d_ws + cnt_bytes);
        scatter_cands<<<B_ * NCH2, 256, 0, stream>>>(conf, gccnt, gcand);
        detect_kernel<true><<<NBLK, NTB, 0, stream>>>(loc, prior, gccnt, gcand, conf, out);
    } else {
        detect_kernel<false><<<NBLK, NTB, 0, stream>>>(loc, prior, nullptr, nullptr, conf, out);
    }
}

// Round 15
// 123.730 us; speedup vs baseline: 1.1533x; 1.1533x over previous
//
#include <hip/hip_runtime.h>
#include <stdint.h>

#define B_ 32
#define P_ 8732
#define C_ 21
#define TOPK 200
#define TGT 228        // count-search acceptance window center [200,256]
#define TGT0 245       // scatter pre-filter: P(gc in [200,256]) ~ 76% -> skip search
#define SUBCAP 28      // per-(task,chunk) capacity; Poisson(7.2) P(>28) ~ 1e-9
#define NCH2 35        // ceil(P_/256) chunks
#define NSLOT (NCH2 * SUBCAP)   // 980 slots/task
#define CONF_T 0.01f
#define NMS_T 0.45f
#define NT 512         // 8-wave blocks: the only shape that packs (R5/R7/R10/R14 evidence)
#define KV4 5          // slow-path strided load: ceil((P_/4)/NT)
#define NTASK (B_ * C_)

__device__ __forceinline__ uint32_t f2s(float f) {
    uint32_t u = __float_as_uint(f);
    return (u & 0x80000000u) ? ~u : (u | 0x80000000u);
}
__device__ __forceinline__ float s2f(uint32_t s) {
    uint32_t b = (s & 0x80000000u) ? (s & 0x7FFFFFFFu) : ~s;
    return __uint_as_float(b);
}
__device__ __forceinline__ uint32_t keyof(float v) {
    return f2s((v > CONF_T) ? v : -1.0f);
}
__device__ __forceinline__ uint32_t thr0() {
    return f2s(1.0f - (float)TGT0 / (float)P_);   // folds to a constant
}

// conf (B,P,C) -> chunked per-task candidate lists. No atomics: ballot prefix
// assigns slots; lane-per-prior LDS reads (stride 21 coprime 32: conflict-free).
__global__ __launch_bounds__(256) void scatter_cands(const float* __restrict__ conf,
                                                     uint32_t* __restrict__ gccnt,
                                                     uint64_t* __restrict__ gcand) {
    const int b = blockIdx.x / NCH2;
    const int ch = blockIdx.x % NCH2;
    const int p0 = ch * 256;
    const int n = min(256, P_ - p0);          // 256 or 28
    const int tid = threadIdx.x;
    const int lane = tid & 63;
    const int wv = tid >> 6;                  // wave id: class slice 0..3
    __shared__ float tile[256 * C_];
    const float4* src4 = (const float4*)(conf + ((size_t)b * P_ + p0) * C_);
    float4* tile4 = (float4*)tile;
    const int tot4 = (n * C_) >> 2;
    for (int i = tid; i < tot4; i += 256) tile4[i] = src4[i];
    __syncthreads();
    const uint32_t T0 = thr0();
    const unsigned long long lmask = (1ull << lane) - 1ull;
    for (int c = (wv == 0 ? 4 : wv); c < C_; c += 4) {   // class 0 output zeroed: skip
        int base = 0;
        uint64_t* dst = gcand + ((size_t)(b * C_ + c) * NCH2 + ch) * SUBCAP;
        #pragma unroll
        for (int itp = 0; itp < 4; ++itp) {
            const int p = itp * 64 + lane;
            bool q = false; uint32_t key = 0;
            if (p < n) {
                key = keyof(tile[p * C_ + c]);   // conflict-free: stride 21 banks
                q = (key >= T0);
            }
            const unsigned long long bm = __ballot(q);
            if (q) {
                int pos = base + (int)__popcll(bm & lmask);
                if (pos < SUBCAP)
                    dst[pos] = ((uint64_t)key << 32) | (uint32_t)(~(uint32_t)(p0 + p));
            }
            base += (int)__popcll(bm);
        }
        if (lane == 0) gccnt[(size_t)(b * C_ + c) * NCH2 + ch] = (uint32_t)base;
    }
}

template<bool HASWS>
__global__ __launch_bounds__(NT, 6) void detect_kernel(
    const float* __restrict__ loc, const float* __restrict__ prior,
    const uint32_t* __restrict__ gccnt, const uint64_t* __restrict__ gcand,
    const float* __restrict__ conf, float* __restrict__ out)
{
    const int task = blockIdx.x;
    const int b = task / C_;
    const int c = task % C_;
    const int tid = threadIdx.x;
    const int lane = tid & 63;
    float* outp = out + (size_t)task * TOPK * 5;

    if (c == 0) {  // out.at[:,0].set(0.0)
        for (int e = tid; e < TOPK * 5; e += NT) outp[e] = 0.0f;
        return;
    }

    __shared__ uint64_t cand[256];
    __shared__ float4 bbox[TOPK];
    __shared__ float bs[TOPK];
    __shared__ unsigned long long msk[TOPK * 4];
    __shared__ unsigned long long vmask[4];
    __shared__ int order[TOPK];
    __shared__ int s_cnt, s_nk;
    __shared__ int s_c2[2];
    __shared__ uint32_t s_ccnt[NCH2];
    __shared__ int s_gc, s_bad;

    const uint32_t T0 = thr0();

    // ---- issue slot + count loads IMMEDIATELY (addresses don't depend on
    //      counts; validity masked later; stale slots filtered by counts) ----
    uint64_t vc0 = 0, vc1 = 0;
    if (HASWS) {
        const uint64_t* gp = gcand + (size_t)task * NSLOT;
        vc0 = gp[tid];                               // tid < 512 < NSLOT
        if (tid + NT < NSLOT) vc1 = gp[tid + NT];
        if (tid < NCH2) s_ccnt[tid] = gccnt[(size_t)task * NCH2 + tid];
    }

    // ---- one-time zeroing (hidden under the in-flight loads) ----
    if (tid == 0) s_cnt = 0;
    if (tid < 2) s_c2[tid] = 0;
    for (int i2 = tid; i2 < TOPK * 4; i2 += NT) msk[i2] = 0ull;
    __syncthreads();
    if (HASWS && tid < 64) {           // wave 0: total + overflow check
        uint32_t cc = (lane < NCH2) ? s_ccnt[lane] : 0u;
        int bad = (cc > SUBCAP) ? 1 : 0;
        int tot = (int)cc;
        #pragma unroll
        for (int d = 1; d < 64; d <<= 1) {
            tot += __shfl_down(tot, d);
            bad |= __shfl_down(bad, d);
        }
        if (lane == 0) { s_gc = tot; s_bad = bad; }
    }
    __syncthreads();

    const bool fast = HASWS && !s_bad && s_gc >= TOPK;   // ~always
    const int gc = HASWS ? s_gc : 0;

    bool val0 = false, val1 = false;
    uint4 kv[KV4];                     // slow path: strided keys
    if (fast) {
        {
            const int ch0 = tid / SUBCAP, i0 = tid - ch0 * SUBCAP;
            val0 = i0 < (int)s_ccnt[ch0];
        }
        const int s1 = tid + NT;
        if (s1 < NSLOT) {
            const int ch1 = s1 / SUBCAP, i1 = s1 - ch1 * SUBCAP;
            val1 = i1 < (int)s_ccnt[ch1];
        }
    } else {
        const float* sp = conf + (size_t)b * P_ * C_ + c;
        #pragma unroll
        for (int r = 0; r < KV4; ++r) {
            uint32_t uu[4];
            #pragma unroll
            for (int c4 = 0; c4 < 4; ++c4) {
                int p = (tid + r * NT) * 4 + c4;
                if (p < P_) {
                    float v = sp[(size_t)p * C_];
                    v = (v > CONF_T) ? v : -1.0f;
                    uu[c4] = f2s(v);
                } else uu[c4] = 0u;
            }
            kv[r] = make_uint4(uu[0], uu[1], uu[2], uu[3]);
        }
    }

    // ---- threshold with count in [200,256], then compact ----
    if (fast) {
        uint32_t vthr = T0;            // gc<=256 (76% of tasks): no search at all
        if (gc > 256) {                // raise threshold within candidates
            const uint32_t k0 = (uint32_t)(vc0 >> 32);
            const uint32_t k1 = (uint32_t)(vc1 >> 32);
            uint32_t lo = T0, hi = 0xFFFFFFFFu;
            uint32_t t;
            {
                const float sc = s2f(T0);
                const float sn = 1.0f - (1.0f - sc) * (float)TGT / (float)gc;
                t = f2s(sn);
                if (!(t > lo && t < hi)) t = lo + ((hi - lo) >> 1);
            }
            for (int it = 0; ; ++it) {
                const int slot = it & 1;
                int my = (val0 && k0 >= t) + (val1 && k1 >= t);
                #pragma unroll
                for (int d = 1; d < 64; d <<= 1) my += __shfl_down(my, d);
                if (lane == 0) atomicAdd(&s_c2[slot], my);
                __syncthreads();
                const int cnt = s_c2[slot];
                __syncthreads();
                if (tid == 0) s_c2[slot] = 0;
                if (cnt >= TOPK && cnt <= 256) { vthr = t; break; }
                if (cnt > 256) lo = t; else hi = t;
                if (hi - lo <= 1) { vthr = lo; break; }
                uint32_t tn = 0;
                bool bis = (it >= 8) || (cnt == 0);
                if (!bis) {
                    const float sc = s2f(t);
                    const float sn = 1.0f - (1.0f - sc) * (float)TGT / (float)cnt;
                    tn = f2s(sn);
                    if (!(tn > lo && tn < hi)) bis = true;
                }
                if (bis) tn = lo + ((hi - lo) >> 1);
                t = tn;
            }
        }
        if (val0 && (uint32_t)(vc0 >> 32) >= vthr) {
            int pos = atomicAdd(&s_cnt, 1);
            if (pos < 256) cand[pos] = vc0;
        }
        if (val1 && (uint32_t)(vc1 >> 32) >= vthr) {
            int pos = atomicAdd(&s_cnt, 1);
            if (pos < 256) cand[pos] = vc1;
        }
    } else {
        // full interpolated count-search over strided keys (rare / no-ws path)
        uint32_t lo = 0u, hi = 0xFFFFFFFFu;
        uint32_t t = f2s(1.0f - (float)TGT / (float)P_);
        uint32_t vthr = 0u;
        for (int it = 0; ; ++it) {
            const int slot = it & 1;
            int my = 0;
            #pragma unroll
            for (int r = 0; r < KV4; ++r)
                my += (kv[r].x >= t) + (kv[r].y >= t) + (kv[r].z >= t) + (kv[r].w >= t);
            #pragma unroll
            for (int d = 1; d < 64; d <<= 1) my += __shfl_down(my, d);
            if (lane == 0) atomicAdd(&s_c2[slot], my);
            __syncthreads();
            const int cnt = s_c2[slot];
            __syncthreads();
            if (tid == 0) s_c2[slot] = 0;
            if (cnt >= TOPK && cnt <= 256) { vthr = t; break; }
            if (cnt > 256) lo = t; else hi = t;
            if (hi - lo <= 1) { vthr = lo; break; }
            uint32_t tn = 0;
            bool bis = (it >= 8) || (cnt == 0);
            if (!bis) {
                const float sc = s2f(t);
                const float sn = 1.0f - (1.0f - sc) * (float)TGT / (float)cnt;
                tn = f2s(sn);
                if (!(tn > lo && tn < hi)) bis = true;
            }
            if (bis) tn = lo + ((hi - lo) >> 1);
            t = tn;
        }
        #pragma unroll
        for (int r = 0; r < KV4; ++r) {
            const int pb = (tid + r * NT) * 4;
            uint32_t uu[4] = {kv[r].x, kv[r].y, kv[r].z, kv[r].w};
            #pragma unroll
            for (int c4 = 0; c4 < 4; ++c4) {
                uint32_t u = uu[c4];
                if (u >= vthr) {
                    int pos = atomicAdd(&s_cnt, 1);
                    if (pos < 256) cand[pos] = ((uint64_t)u << 32) | (uint32_t)(~(uint32_t)(pb + c4));
                }
            }
        }
    }
    __syncthreads();
    if (tid < 256 && tid >= s_cnt) cand[tid] = 0ull;   // pad sorts to the end
    __syncthreads();

    // ---- bitonic sort 256 keys desc (val desc, idx asc) == jax.lax.top_k ----
    uint64_t v = (tid < 256) ? cand[tid] : 0ull;
    for (int kk = 2; kk <= 256; kk <<= 1) {
        for (int j = kk >> 1; j > 0; j >>= 1) {
            if (j >= 64) {
                __syncthreads();
                if (tid < 256) cand[tid] = v;
                __syncthreads();
                if (tid < 256) {
                    uint64_t pv = cand[tid ^ j];
                    bool keepmax = (((tid & j) == 0) == ((tid & kk) == 0));
                    v = keepmax ? (v > pv ? v : pv) : (v < pv ? v : pv);
                }
            } else if (tid < 256) {
                uint64_t pv = __shfl_xor(v, j);
                bool keepmax = (((tid & j) == 0) == ((tid & kk) == 0));
                v = keepmax ? (v > pv ? v : pv) : (v < pv ? v : pv);
            }
        }
    }

    // ---- decode top-200 boxes (exact ref f32 op order, no contraction) ----
    float my_sc = -1.0f;
    if (tid < TOPK) {
        uint32_t su = (uint32_t)(v >> 32);
        int p = (int)(~(uint32_t)v);
        my_sc = s2f(su);
        const float4 l4 = *(const float4*)(loc + ((size_t)b * P_ + p) * 4);
        const float4 pr = *(const float4*)(prior + (size_t)p * 4);
        float cx = __fadd_rn(pr.x, __fmul_rn(__fmul_rn(l4.x, 0.1f), pr.z));
        float cy = __fadd_rn(pr.y, __fmul_rn(__fmul_rn(l4.y, 0.1f), pr.w));
        float ew = (float)exp((double)__fmul_rn(l4.z, 0.2f));
        float eh = (float)exp((double)__fmul_rn(l4.w, 0.2f));
        float w  = __fmul_rn(pr.z, ew);
        float h  = __fmul_rn(pr.w, eh);
        float x1 = __fsub_rn(cx, __fmul_rn(w, 0.5f));
        float y1 = __fsub_rn(cy, __fmul_rn(h, 0.5f));
        float x2 = __fadd_rn(x1, w);
        float y2 = __fadd_rn(y1, h);
        bs[tid] = my_sc;
        bbox[tid] = make_float4(x1, y1, x2, y2);
    }
    {
        unsigned long long bm = __ballot(tid < TOPK && my_sc > CONF_T);
        if (lane == 0 && tid < 256) vmask[tid >> 6] = bm;
    }
    __syncthreads();

    // ---- pairwise IoU: balanced row-pairing; areas recomputed inline ----
    if (tid < 500) {
        const int rp = tid / 5;        // row-pair id in [0,100)
        const int s  = tid - rp * 5;   // sub-lane in [0,5)
        #pragma unroll
        for (int pass = 0; pass < 2; ++pass) {
            const int j  = pass ? (199 - rp) : rp;
            const int i0 = j + 1 + s;
            const float4 bj = bbox[j];
            const float  aj = __fmul_rn(__fsub_rn(bj.z, bj.x), __fsub_rn(bj.w, bj.y));
            for (int i = i0; i < TOPK; i += 5) {
                const float4 bi = bbox[i];
                float xx1 = fmaxf(bj.x, bi.x);
                float yy1 = fmaxf(bj.y, bi.y);
                float xx2 = fminf(bj.z, bi.z);
                float yy2 = fminf(bj.w, bi.w);
                float dx = fmaxf(__fsub_rn(xx2, xx1), 0.0f);
                float dy = fmaxf(__fsub_rn(yy2, yy1), 0.0f);
                float inter = __fmul_rn(dx, dy);
                if (inter > 0.0f) {
                    float ai = __fmul_rn(__fsub_rn(bi.z, bi.x), __fsub_rn(bi.w, bi.y));
                    float uni = __fsub_rn(__fadd_rn(aj, ai), inter);
                    float t45 = __fmul_rn(NMS_T, uni);
                    float mar = __fmul_rn(t45, 1e-6f);
                    bool sup;
                    if (inter > __fadd_rn(t45, mar)) sup = true;
                    else if (inter < __fsub_rn(t45, mar)) sup = false;
                    else sup = (inter / uni > NMS_T);   // exact IEEE path, tie band only
                    if (sup) atomicOr(&msk[j * 4 + (i >> 6)], 1ull << (i & 63));
                }
            }
        }
    }
    __syncthreads();

    // ---- greedy NMS: word-blocked wave-0 scan (1 shfl/pick, deferred cross-word OR) ----
    if (tid < 64) {
        const int L = tid;
        auto or_reduce = [&](unsigned long long x) {
            #pragma unroll
            for (int d = 1; d < 64; d <<= 1) x |= __shfl_xor(x, d);
            return x;
        };
        unsigned long long s1 = 0, s2 = 0, s3 = 0;   // incoming suppression, words 1..3
        int nk = 0;
        #pragma unroll
        for (int w = 0; w < 4; ++w) {
            const int j = (w << 6) | L;
            unsigned long long r0 = 0, r1 = 0, r2 = 0, r3 = 0;
            if (j < TOPK) {
                const unsigned long long* mr = &msk[j * 4];
                r0 = mr[0]; r1 = mr[1]; r2 = mr[2]; r3 = mr[3];
            }
            const unsigned long long rself = (w == 0) ? r0 : (w == 1) ? r1
                                           : (w == 2) ? r2 : r3;
            unsigned long long sw = (w == 0) ? 0ull : (w == 1) ? s1
                                  : (w == 2) ? s2 : s3;
            unsigned long long alive = vmask[w] & ~sw;
            unsigned long long pm = 0;
            while (alive) {
                int jl = __ffsll(alive) - 1;
                if (L == 0) order[nk] = (w << 6) | jl;
                ++nk;
                sw |= __shfl(rself, jl);             // suppression within this word
                pm |= (1ull << jl);
                alive &= ~(sw | (1ull << jl));
            }
            if (pm) {   // deferred: OR picked rows' later-word masks (mask bits are i>j only)
                const bool picked = (pm >> L) & 1ull;
                if (w == 0) {
                    s1 |= or_reduce(picked ? r1 : 0ull);
                    s2 |= or_reduce(picked ? r2 : 0ull);
                    s3 |= or_reduce(picked ? r3 : 0ull);
                } else if (w == 1) {
                    s2 |= or_reduce(picked ? r2 : 0ull);
                    s3 |= or_reduce(picked ? r3 : 0ull);
                } else if (w == 2) {
                    s3 |= or_reduce(picked ? r3 : 0ull);
                }
            }
        }
        if (L == 0) s_nk = nk;
    }
    __syncthreads();

    // ---- compacted output ----
    const int nk = s_nk;
    for (int e = tid; e < TOPK * 5; e += NT) {
        int r = e / 5;
        int f = e - r * 5;
        float val = 0.0f;
        if (r < nk) {
            int j = order[r];
            float4 bb = bbox[j];
            val = (f == 0) ? bs[j] : (f == 1) ? bb.x : (f == 2) ? bb.y
                : (f == 3) ? bb.z : bb.w;
        }
        outp[e] = val;
    }
}

extern "C" void kernel_launch(void* const* d_in, const int* in_sizes, int n_in,
                              void* d_out, int out_size, void* d_ws, size_t ws_size,
                              hipStream_t stream) {
    const float* loc   = (const float*)d_in[0];
    const float* conf  = (const float*)d_in[1];
    const float* prior = (const float*)d_in[2];
    float* out = (float*)d_out;

    const size_t cnt_bytes  = (size_t)NTASK * NCH2 * sizeof(uint32_t);   // 8-aligned
    const size_t cand_bytes = (size_t)NTASK * NSLOT * sizeof(uint64_t);  // ~5.3 MB
    if (ws_size >= cnt_bytes + cand_bytes) {
        uint32_t* gccnt = (uint32_t*)d_ws;
        uint64_t* gcand = (uint64_t*)((char*)d_ws + cnt_bytes);
        scatter_cands<<<B_ * NCH2, 256, 0, stream>>>(conf, gccnt, gcand);
        detect_kernel<true><<<NTASK, NT, 0, stream>>>(loc, prior, gccnt, gcand, conf, out);
    } else {
        detect_kernel<false><<<NTASK, NT, 0, stream>>>(loc, prior, nullptr, nullptr, conf, out);
    }
}